// Round 1
// baseline (109.442 us; speedup 1.0000x reference)
//
#include <hip/hip_runtime.h>
#include <math.h>

// LML layer: per row solve sum_j sigmoid(x_j + nu) = N (N=5), output sigmoid(x+nu).
// One wave (64 lanes) per row; 16 elements/lane in registers as E_j = exp(-x_j);
// sigmoid(x_j + nu) = rcp(1 + exp(-nu)*E_j). Binary bisection, 30 fixed iters.
// Bracket: lo = -max-6 (f<0 since 1024*sig(-6)=2.53<5), hi = -min+7 (f>0 since
// 1024*sig(7)>1022>5). Wave butterfly reduce -> sum identical on all lanes ->
// uniform branch, no LDS/barriers.

constexpr int COLS = 1024;
constexpr int NTOP = 5;
constexpr int VPL  = COLS / 64;   // 16 values per lane
constexpr int WPB  = 4;           // waves (rows) per block
constexpr int NBIS = 30;

__device__ __forceinline__ float wave_sum(float v) {
#pragma unroll
    for (int m = 32; m >= 1; m >>= 1) v += __shfl_xor(v, m, 64);
    return v;
}
__device__ __forceinline__ float wave_max(float v) {
#pragma unroll
    for (int m = 32; m >= 1; m >>= 1) v = fmaxf(v, __shfl_xor(v, m, 64));
    return v;
}
__device__ __forceinline__ float wave_min(float v) {
#pragma unroll
    for (int m = 32; m >= 1; m >>= 1) v = fminf(v, __shfl_xor(v, m, 64));
    return v;
}

__global__ __launch_bounds__(WPB * 64) void lml_kernel(
        const float* __restrict__ x, float* __restrict__ y, int rows) {
    const int wave = threadIdx.x >> 6;
    const int lane = threadIdx.x & 63;
    const int row  = blockIdx.x * WPB + wave;
    if (row >= rows) return;

    const float* xr = x + (size_t)row * COLS;
    float*       yr = y + (size_t)row * COLS;

    float E[VPL];
    float vmax = -INFINITY, vmin = INFINITY;
#pragma unroll
    for (int w = 0; w < VPL / 4; ++w) {
        // element offset w*256 + lane*4 .. +3 : each float4 load is a fully
        // coalesced contiguous 1 KiB wave access.
        float4 v = *reinterpret_cast<const float4*>(xr + w * 256 + lane * 4);
        vmax = fmaxf(vmax, fmaxf(fmaxf(v.x, v.y), fmaxf(v.z, v.w)));
        vmin = fminf(vmin, fminf(fminf(v.x, v.y), fminf(v.z, v.w)));
        E[w * 4 + 0] = __expf(-v.x);
        E[w * 4 + 1] = __expf(-v.y);
        E[w * 4 + 2] = __expf(-v.z);
        E[w * 4 + 3] = __expf(-v.w);
    }
    vmax = wave_max(vmax);
    vmin = wave_min(vmin);

    float lo = -vmax - 6.0f;   // f(lo) < 0 guaranteed
    float hi = -vmin + 7.0f;   // f(hi) > 0 guaranteed

#pragma unroll 1
    for (int it = 0; it < NBIS; ++it) {
        float mid = 0.5f * (lo + hi);
        float u = __expf(-mid);
        float partial = 0.0f;
#pragma unroll
        for (int j = 0; j < VPL; ++j)
            partial += __builtin_amdgcn_rcpf(fmaf(u, E[j], 1.0f));
        float s = wave_sum(partial);   // bitwise-identical on all 64 lanes
        if (s < (float)NTOP) lo = mid; else hi = mid;
    }

    const float nu = 0.5f * (lo + hi);
    const float u  = __expf(-nu);
#pragma unroll
    for (int w = 0; w < VPL / 4; ++w) {
        float4 o;
        o.x = __builtin_amdgcn_rcpf(fmaf(u, E[w * 4 + 0], 1.0f));
        o.y = __builtin_amdgcn_rcpf(fmaf(u, E[w * 4 + 1], 1.0f));
        o.z = __builtin_amdgcn_rcpf(fmaf(u, E[w * 4 + 2], 1.0f));
        o.w = __builtin_amdgcn_rcpf(fmaf(u, E[w * 4 + 3], 1.0f));
        *reinterpret_cast<float4*>(yr + w * 256 + lane * 4) = o;
    }
}

extern "C" void kernel_launch(void* const* d_in, const int* in_sizes, int n_in,
                              void* d_out, int out_size, void* d_ws, size_t ws_size,
                              hipStream_t stream) {
    const float* x = (const float*)d_in[0];
    float* y = (float*)d_out;
    const int rows = in_sizes[0] / COLS;   // 8192
    const int grid = (rows + WPB - 1) / WPB;
    lml_kernel<<<grid, WPB * 64, 0, stream>>>(x, y, rows);
}

// Round 2
// 84.301 us; speedup vs baseline: 1.2982x; 1.2982x over previous
//
#include <hip/hip_runtime.h>
#include <math.h>

// LML layer: per row solve sum_j sigmoid(x_j + nu) = N (N=5), output sigmoid(x+nu).
// One wave (64 lanes) per row; 16 elements/lane in registers as E_j = exp(-x_j);
// sigmoid(x_j + nu) = rcp(1 + exp(-nu)*E_j).
//
// Root-finder (replaces reference's 20x10 multi-section search):
//   sigmoid(t) <= e^t  =>  nu0 = log(N / sum_j e^{x_j}) is a guaranteed LOWER
//   bound on the root, and for left-tail data (all s_j << 1, f convex) it is
//   within ~0.1 of it. 4 bracket-safeguarded Newton iterations with
//   f'(nu) = sum_j s_j(1-s_j) converge to ~1e-6 (threshold needs only ~2e-2).
// All reduced sums are butterfly wave-reductions -> bitwise identical across
// lanes -> every branch is wave-uniform. No LDS, no barriers.

constexpr int COLS = 1024;
constexpr int NTOP = 5;
constexpr int VPL  = COLS / 64;   // 16 values per lane
constexpr int WPB  = 4;           // waves (rows) per block
constexpr int NNEWT = 4;

__device__ __forceinline__ float wave_sum(float v) {
#pragma unroll
    for (int m = 32; m >= 1; m >>= 1) v += __shfl_xor(v, m, 64);
    return v;
}
__device__ __forceinline__ float wave_min(float v) {
#pragma unroll
    for (int m = 32; m >= 1; m >>= 1) v = fminf(v, __shfl_xor(v, m, 64));
    return v;
}

__global__ __launch_bounds__(WPB * 64) void lml_kernel(
        const float* __restrict__ x, float* __restrict__ y, int rows) {
    const int wave = threadIdx.x >> 6;
    const int lane = threadIdx.x & 63;
    const int row  = blockIdx.x * WPB + wave;
    if (row >= rows) return;

    const float* xr = x + (size_t)row * COLS;
    float*       yr = y + (size_t)row * COLS;

    float E[VPL];
    float vmin = INFINITY;
    float s0 = 0.0f;   // sum of e^{x_j}
#pragma unroll
    for (int w = 0; w < VPL / 4; ++w) {
        // contiguous 1 KiB coalesced wave access
        float4 v = *reinterpret_cast<const float4*>(xr + w * 256 + lane * 4);
        vmin = fminf(vmin, fminf(fminf(v.x, v.y), fminf(v.z, v.w)));
        float e0 = __expf(-v.x), e1 = __expf(-v.y);
        float e2 = __expf(-v.z), e3 = __expf(-v.w);
        E[w * 4 + 0] = e0; E[w * 4 + 1] = e1;
        E[w * 4 + 2] = e2; E[w * 4 + 3] = e3;
        s0 += __builtin_amdgcn_rcpf(e0) + __builtin_amdgcn_rcpf(e1)
            + __builtin_amdgcn_rcpf(e2) + __builtin_amdgcn_rcpf(e3);
    }
    vmin = wave_min(vmin);
    s0   = wave_sum(s0);

    // nu0 = log(N / sum e^x): guaranteed f(nu0) <= 0 (lower bound on root).
    float nu = __logf((float)NTOP) - __logf(s0);
    float lo = nu - 1e-3f;         // tiny slack against rcp/log rounding
    float hi = -vmin + 7.0f;       // f(hi) >= 1024*sig(7) - 5 > 0

#pragma unroll 1
    for (int it = 0; it < NNEWT; ++it) {
        float u = __expf(-nu);
        float S = 0.0f, D = 0.0f;
#pragma unroll
        for (int j = 0; j < VPL; ++j) {
            float s = __builtin_amdgcn_rcpf(fmaf(u, E[j], 1.0f));
            S += s;
            D += fmaf(-s, s, s);   // s*(1-s)
        }
        S = wave_sum(S);           // identical on all lanes
        D = wave_sum(D);
        float f = S - (float)NTOP;
        if (f < 0.0f) lo = nu; else hi = nu;           // wave-uniform
        float step = f * __builtin_amdgcn_rcpf(D);
        float nun = nu - step;
        if (!(nun > lo && nun < hi)) nun = 0.5f * (lo + hi);  // safeguard
        nu = nun;
    }

    const float u = __expf(-nu);
#pragma unroll
    for (int w = 0; w < VPL / 4; ++w) {
        float4 o;
        o.x = __builtin_amdgcn_rcpf(fmaf(u, E[w * 4 + 0], 1.0f));
        o.y = __builtin_amdgcn_rcpf(fmaf(u, E[w * 4 + 1], 1.0f));
        o.z = __builtin_amdgcn_rcpf(fmaf(u, E[w * 4 + 2], 1.0f));
        o.w = __builtin_amdgcn_rcpf(fmaf(u, E[w * 4 + 3], 1.0f));
        *reinterpret_cast<float4*>(yr + w * 256 + lane * 4) = o;
    }
}

extern "C" void kernel_launch(void* const* d_in, const int* in_sizes, int n_in,
                              void* d_out, int out_size, void* d_ws, size_t ws_size,
                              hipStream_t stream) {
    const float* x = (const float*)d_in[0];
    float* y = (float*)d_out;
    const int rows = in_sizes[0] / COLS;   // 8192
    const int grid = (rows + WPB - 1) / WPB;
    lml_kernel<<<grid, WPB * 64, 0, stream>>>(x, y, rows);
}

// Round 3
// 81.397 us; speedup vs baseline: 1.3446x; 1.0357x over previous
//
#include <hip/hip_runtime.h>
#include <math.h>

// LML layer: per row solve sum_j sigmoid(x_j + nu) = N (N=5), output sigmoid(x+nu).
// One wave (64 lanes) per row; 16 elements/lane in registers as E_j = exp(+x_j).
//
// Change of variable u = exp(-nu):  sigmoid(x_j+nu) = E_j / (E_j + u).
//   g(u) = sum_j E_j/(E_j+u) - N   is convex & strictly decreasing for u>0
//   for ANY data (each term is convex). u0 = (sum E)/N gives
//   g(u0) = sum E/(E+u0) < sum E/u0 = N  =>  g(u0) < 0, and convexity makes
//   plain Newton globally convergent (first step left, then monotone from the
//   left). No brackets, no exp/log anywhere in the solve or epilogue.
// Butterfly wave-reductions -> sums bitwise identical across lanes -> all
// control flow wave-uniform. No LDS, no barriers.

constexpr int COLS  = 1024;
constexpr int NTOP  = 5;
constexpr int VPL   = COLS / 64;   // 16 values per lane
constexpr int WPB   = 4;           // waves (rows) per block
constexpr int NNEWT = 3;

__device__ __forceinline__ float wave_sum(float v) {
#pragma unroll
    for (int m = 32; m >= 1; m >>= 1) v += __shfl_xor(v, m, 64);
    return v;
}
// Two interleaved reductions so the shfl latencies pipeline.
__device__ __forceinline__ void wave_sum2(float& a, float& b) {
#pragma unroll
    for (int m = 32; m >= 1; m >>= 1) {
        float ta = __shfl_xor(a, m, 64);
        float tb = __shfl_xor(b, m, 64);
        a += ta; b += tb;
    }
}

__global__ __launch_bounds__(WPB * 64) void lml_kernel(
        const float* __restrict__ x, float* __restrict__ y, int rows) {
    const int wave = threadIdx.x >> 6;
    const int lane = threadIdx.x & 63;
    const int row  = blockIdx.x * WPB + wave;
    if (row >= rows) return;

    const float* xr = x + (size_t)row * COLS;
    float*       yr = y + (size_t)row * COLS;

    constexpr float L2E = 1.4426950408889634f;   // log2(e)

    float E[VPL];
    float s0 = 0.0f;   // sum of e^{x_j}  (free: no rcp needed)
#pragma unroll
    for (int w = 0; w < VPL / 4; ++w) {
        // contiguous 1 KiB coalesced wave access
        float4 v = *reinterpret_cast<const float4*>(xr + w * 256 + lane * 4);
        float e0 = __builtin_amdgcn_exp2f(v.x * L2E);
        float e1 = __builtin_amdgcn_exp2f(v.y * L2E);
        float e2 = __builtin_amdgcn_exp2f(v.z * L2E);
        float e3 = __builtin_amdgcn_exp2f(v.w * L2E);
        E[w * 4 + 0] = e0; E[w * 4 + 1] = e1;
        E[w * 4 + 2] = e2; E[w * 4 + 3] = e3;
        s0 += (e0 + e1) + (e2 + e3);
    }
    s0 = wave_sum(s0);                 // identical on all lanes

    float u = s0 * (1.0f / (float)NTOP);   // u0: g(u0) < 0 guaranteed

#pragma unroll 1
    for (int it = 0; it < NNEWT; ++it) {
        float G = 0.0f, H = 0.0f;
#pragma unroll
        for (int j = 0; j < VPL; ++j) {
            float r = __builtin_amdgcn_rcpf(E[j] + u);
            float t = E[j] * r;        // sigmoid value
            G += t;
            H = fmaf(t, r, H);         // -g'(u) = sum E/(E+u)^2
        }
        wave_sum2(G, H);               // identical on all lanes
        // Newton: u -= g/g' = u + (G-N)/H
        u = fmaf(G - (float)NTOP, __builtin_amdgcn_rcpf(H), u);
        u = fmaxf(u, 1e-30f);          // paranoia clamp, never hit for sane data
    }

#pragma unroll
    for (int w = 0; w < VPL / 4; ++w) {
        float4 o;
        o.x = E[w * 4 + 0] * __builtin_amdgcn_rcpf(E[w * 4 + 0] + u);
        o.y = E[w * 4 + 1] * __builtin_amdgcn_rcpf(E[w * 4 + 1] + u);
        o.z = E[w * 4 + 2] * __builtin_amdgcn_rcpf(E[w * 4 + 2] + u);
        o.w = E[w * 4 + 3] * __builtin_amdgcn_rcpf(E[w * 4 + 3] + u);
        *reinterpret_cast<float4*>(yr + w * 256 + lane * 4) = o;
    }
}

extern "C" void kernel_launch(void* const* d_in, const int* in_sizes, int n_in,
                              void* d_out, int out_size, void* d_ws, size_t ws_size,
                              hipStream_t stream) {
    const float* x = (const float*)d_in[0];
    float* y = (float*)d_out;
    const int rows = in_sizes[0] / COLS;   // 8192
    const int grid = (rows + WPB - 1) / WPB;
    lml_kernel<<<grid, WPB * 64, 0, stream>>>(x, y, rows);
}

// Round 5
// 80.182 us; speedup vs baseline: 1.3649x; 1.0151x over previous
//
#include <hip/hip_runtime.h>
#include <math.h>

// LML layer: per row solve sum_j sigmoid(x_j + nu) = N (N=5), output sigmoid(x+nu).
// One wave (64 lanes) per row; 16 elements/lane in registers as E_j = exp(+x_j).
//
// u = exp(-nu):  sigmoid(x_j+nu) = E_j/(E_j+u).
//   g(u) = sum E/(E+u) - N is convex, strictly decreasing for u>0 (any data).
//   u0 = (sum E)/N  =>  g(u0) < 0; convexity => plain Newton globally
//   convergent (one left overshoot, then monotone from the left).
// Pass structure (3 passes over E, 50 trans ops/lane):
//   pass 1: load x, E=exp2(x*log2e), s0 = sum E   (no rcp needed)
//   pass 2: Newton iter A at u0 -> u1
//   pass 3: Newton iter B at u1: keep t=E/(E+u1), tr=t*r -> step delta,
//           and emit y = t - tr*delta (1st-order Taylor; 2nd-order err ~4e-8)
// Butterfly wave-reductions -> sums bitwise identical across lanes -> all
// control flow wave-uniform. No LDS, no barriers. NT stores (streaming out)
// via native clang vector type (HIP float4 is a class the builtin rejects).

constexpr int COLS = 1024;
constexpr int NTOP = 5;
constexpr int VPL  = COLS / 64;   // 16 values per lane
constexpr int WPB  = 4;           // waves (rows) per block

typedef float vfloat4 __attribute__((ext_vector_type(4)));

__device__ __forceinline__ float wave_sum(float v) {
#pragma unroll
    for (int m = 32; m >= 1; m >>= 1) v += __shfl_xor(v, m, 64);
    return v;
}
// Two interleaved reductions so the shfl latencies pipeline.
__device__ __forceinline__ void wave_sum2(float& a, float& b) {
#pragma unroll
    for (int m = 32; m >= 1; m >>= 1) {
        float ta = __shfl_xor(a, m, 64);
        float tb = __shfl_xor(b, m, 64);
        a += ta; b += tb;
    }
}

__global__ __launch_bounds__(WPB * 64) void lml_kernel(
        const float* __restrict__ x, float* __restrict__ y, int rows) {
    const int wave = threadIdx.x >> 6;
    const int lane = threadIdx.x & 63;
    const int row  = blockIdx.x * WPB + wave;
    if (row >= rows) return;

    const float* xr = x + (size_t)row * COLS;
    float*       yr = y + (size_t)row * COLS;

    constexpr float L2E = 1.4426950408889634f;   // log2(e)

    // ---- pass 1: load + exp, row-sum of E ----
    float E[VPL];
    float s0 = 0.0f;
#pragma unroll
    for (int w = 0; w < VPL / 4; ++w) {
        vfloat4 v = *reinterpret_cast<const vfloat4*>(xr + w * 256 + lane * 4);
        float e0 = __builtin_amdgcn_exp2f(v.x * L2E);
        float e1 = __builtin_amdgcn_exp2f(v.y * L2E);
        float e2 = __builtin_amdgcn_exp2f(v.z * L2E);
        float e3 = __builtin_amdgcn_exp2f(v.w * L2E);
        E[w * 4 + 0] = e0; E[w * 4 + 1] = e1;
        E[w * 4 + 2] = e2; E[w * 4 + 3] = e3;
        s0 += (e0 + e1) + (e2 + e3);
    }
    s0 = wave_sum(s0);                     // identical on all lanes

    float u = s0 * (1.0f / (float)NTOP);   // u0: g(u0) < 0 guaranteed

    // ---- pass 2: Newton iteration A ----
    {
        float G = 0.0f, H = 0.0f;
#pragma unroll
        for (int j = 0; j < VPL; ++j) {
            float r = __builtin_amdgcn_rcpf(E[j] + u);
            float t = E[j] * r;            // sigmoid value
            G += t;
            H = fmaf(t, r, H);             // -g'(u) = sum E/(E+u)^2
        }
        wave_sum2(G, H);
        u = fmaf(G - (float)NTOP, __builtin_amdgcn_rcpf(H), u);
        u = fmaxf(u, 1e-30f);              // paranoia, never hit for sane data
    }

    // ---- pass 3: Newton iteration B fused with epilogue (Taylor) ----
    float t[VPL], tr[VPL];
    float G = 0.0f, H = 0.0f;
#pragma unroll
    for (int j = 0; j < VPL; ++j) {
        float r  = __builtin_amdgcn_rcpf(E[j] + u);
        float tj = E[j] * r;
        float cj = tj * r;                 // dy/du magnitude = E/(E+u)^2
        t[j] = tj; tr[j] = cj;
        G += tj;
        H += cj;
    }
    wave_sum2(G, H);
    const float delta = (G - (float)NTOP) * __builtin_amdgcn_rcpf(H); // u step

#pragma unroll
    for (int w = 0; w < VPL / 4; ++w) {
        vfloat4 o;
        o.x = fmaf(-delta, tr[w * 4 + 0], t[w * 4 + 0]);
        o.y = fmaf(-delta, tr[w * 4 + 1], t[w * 4 + 1]);
        o.z = fmaf(-delta, tr[w * 4 + 2], t[w * 4 + 2]);
        o.w = fmaf(-delta, tr[w * 4 + 3], t[w * 4 + 3]);
        __builtin_nontemporal_store(o, reinterpret_cast<vfloat4*>(yr + w * 256 + lane * 4));
    }
}

extern "C" void kernel_launch(void* const* d_in, const int* in_sizes, int n_in,
                              void* d_out, int out_size, void* d_ws, size_t ws_size,
                              hipStream_t stream) {
    const float* x = (const float*)d_in[0];
    float* y = (float*)d_out;
    const int rows = in_sizes[0] / COLS;   // 8192
    const int grid = (rows + WPB - 1) / WPB;
    lml_kernel<<<grid, WPB * 64, 0, stream>>>(x, y, rows);
}